// Round 2
// baseline (3953.175 us; speedup 1.0000x reference)
//
#include <hip/hip_runtime.h>
#include <stdint.h>

#define NN 10000      // nodes
#define NE 160000     // edges (paired: e and e^1 are fwd/rev)
#define HID 300
#define NF 133
#define EF 14
#define NG 64

#define BR 64         // rows per GEMM block (64-aligned => complete edge pairs)
#define KT 32         // k-tile
#define WC 320        // padded LDS width for W tile

__device__ __forceinline__ float bf2f(unsigned short u) {
  union { unsigned int i; float f; } x; x.i = ((unsigned int)u) << 16; return x.f;
}
__device__ __forceinline__ unsigned short f2bf(float f) {
  union { float f; unsigned int i; } x; x.f = f;
  unsigned int r = x.i + 0x7fffu + ((x.i >> 16) & 1u);
  return (unsigned short)(r >> 16);
}

// ---------------- small utilities ----------------
__global__ void zero_kernel(int* __restrict__ p, int n) {
  int i = blockIdx.x * 256 + threadIdx.x;
  if (i < n) p[i] = 0;
}

// ---------------- CSR build over col ----------------
__global__ void hist_kernel(const int* __restrict__ col, int* __restrict__ cnt) {
  int e = blockIdx.x * 256 + threadIdx.x;
  if (e < NE) atomicAdd(&cnt[col[e]], 1);
}

__global__ void scan_kernel(const int* __restrict__ cnt, int* __restrict__ indptr) {
  __shared__ int part[1024];
  int t = threadIdx.x;
  int base = t * 10;
  int loc[10];
  int s = 0;
  #pragma unroll
  for (int i = 0; i < 10; ++i) {
    int n = base + i;
    int v = (n < NN) ? cnt[n] : 0;
    loc[i] = s; s += v;
  }
  part[t] = s;
  __syncthreads();
  for (int off = 1; off < 1024; off <<= 1) {
    int v = part[t];
    int u = (t >= off) ? part[t - off] : 0;
    __syncthreads();
    part[t] = v + u;
    __syncthreads();
  }
  int pre = (t == 0) ? 0 : part[t - 1];
  #pragma unroll
  for (int i = 0; i < 10; ++i) {
    int n = base + i;
    if (n <= NN) indptr[n] = pre + loc[i];
  }
}

// consumes cnt back to zero (self-restoring across graph replays)
__global__ void scatter_kernel(const int* __restrict__ col, const int* __restrict__ indptr,
                               int* __restrict__ cnt, int* __restrict__ eids) {
  int e = blockIdx.x * 256 + threadIdx.x;
  if (e < NE) {
    int v = col[e];
    int p = atomicSub(&cnt[v], 1) - 1;   // order within segment irrelevant for sum
    eids[indptr[v] + p] = e;
  }
}

// ---------------- segment_sum(h[bf16], col) -> a[f32] via CSR ----------------
__global__ void segsum_kernel(const unsigned short* __restrict__ h,
                              const int* __restrict__ indptr, const int* __restrict__ eids,
                              float* __restrict__ a) {
  int v = blockIdx.x;
  int t = threadIdx.x;
  int beg = indptr[v], end = indptr[v + 1];
  float s0 = 0.f, s1 = 0.f;
  for (int p = beg; p < end; ++p) {
    int e = eids[p];
    const unsigned short* hr = h + (size_t)e * HID;
    s0 += bf2f(hr[t]);
    if (t < HID - 256) s1 += bf2f(hr[256 + t]);
  }
  a[(size_t)v * HID + t] = s0;
  if (t < HID - 256) a[(size_t)v * HID + 256 + t] = s1;
}

// ---------------- full-width tiled GEMM (64 rows x 300 cols per block) ------
// MODE 0: edge_init  h0 = relu([x[row]|ea] @ W + b); also copy into h
// MODE 1: conv       h[e] = relu((a[row[e]] - bf(h[e^1])) @ W + b + bf(h0[e]))
//                    IN-PLACE on h: block owns rows [r0,r0+64); pairs e,e^1 are
//                    both inside the tile; all reads precede epilogue writes.
// MODE 2: node MLP   hn = relu([x|s] @ W + b)  (f32 out)
template<int MODE>
__global__ __launch_bounds__(256, 2)
void gemm_kernel(const float* __restrict__ xin,
                 const int* __restrict__ rowidx,
                 const float* __restrict__ aux,          // MODE0: edge_attr ; MODE2: s
                 const float* __restrict__ agg,          // MODE1: a
                 const unsigned short* hcur,             // MODE1 in (aliases outA!)
                 const unsigned short* __restrict__ h0,
                 const float* __restrict__ Wm,           // [K x HID] row-major
                 const float* __restrict__ bias,         // [HID]
                 unsigned short* outA,                   // bf16 out (MODE0/1)
                 unsigned short* outB,                   // MODE0 second copy
                 float* __restrict__ outF,               // MODE2 f32 out
                 int nrows, int K)
{
  __shared__ float A_s[BR * 36];     // 64 rows x 32 k, XOR-swizzled 4-float granules
  __shared__ float W_s[KT * WC];     // 32 k x 320 cols (zero-padded)
  __shared__ int rowv[BR];

  const int t = threadIdx.x;
  const int tx = t & 15;             // column group
  const int ty = t >> 4;             // row group 0..15
  const int r0 = blockIdx.x * BR;

  if (MODE != 2 && t < BR) rowv[t] = rowidx[r0 + t];
  __syncthreads();

  float acc[4][5][4];                // 4 rows x (5 passes x 4 cols) = 80
  #pragma unroll
  for (int i = 0; i < 4; ++i)
    #pragma unroll
    for (int p = 0; p < 5; ++p)
      #pragma unroll
      for (int j = 0; j < 4; ++j) acc[i][p][j] = 0.f;

  const int ktiles = (K + KT - 1) / KT;
  for (int kt = 0; kt < ktiles; ++kt) {
    const int kb = kt * KT;
    // ---- stage A: 64 rows x 8 granules = 512 float4, 2 per thread ----
    #pragma unroll
    for (int it = 0; it < 2; ++it) {
      const int idx = t + it * 256;
      const int e = idx >> 3, kg = idx & 7;
      const int k = kb + (kg << 2);
      float4 v = make_float4(0.f, 0.f, 0.f, 0.f);
      if (MODE == 0) {
        const int r = rowv[e];
        float vv[4];
        #pragma unroll
        for (int q = 0; q < 4; ++q) {
          const int kk = k + q; float f = 0.f;
          if (kk < NF) f = xin[(size_t)r * NF + kk];
          else if (kk < NF + EF) f = aux[(size_t)(r0 + e) * EF + (kk - NF)];
          vv[q] = f;
        }
        v = make_float4(vv[0], vv[1], vv[2], vv[3]);
      } else if (MODE == 1) {
        if (k + 3 < HID) {
          const int r = rowv[e];
          const float4 av = *(const float4*)(agg + (size_t)r * HID + k);
          const int ep = (r0 + e) ^ 1;
          const ushort4 hv = *(const ushort4*)(hcur + (size_t)ep * HID + k);
          v = make_float4(av.x - bf2f(hv.x), av.y - bf2f(hv.y),
                          av.z - bf2f(hv.z), av.w - bf2f(hv.w));
        }
      } else {
        const int r = r0 + e;
        if (r < nrows) {
          float vv[4];
          #pragma unroll
          for (int q = 0; q < 4; ++q) {
            const int kk = k + q; float f = 0.f;
            if (kk < NF) f = xin[(size_t)r * NF + kk];
            else if (kk < NF + HID) f = aux[(size_t)r * HID + (kk - NF)];
            vv[q] = f;
          }
          v = make_float4(vv[0], vv[1], vv[2], vv[3]);
        }
      }
      *(float4*)(A_s + e * 36 + ((kg ^ ((e >> 2) & 7)) << 2)) = v;
    }
    // ---- stage W: 32 k-rows x 320 cols = 2560 float4, 10 per thread ----
    #pragma unroll
    for (int it = 0; it < 10; ++it) {
      const int idx = t + it * 256;      // 0..2559
      const int kr = idx / 80;           // k-row 0..31
      const int g  = idx - kr * 80;      // granule 0..79
      const int j  = g << 2;
      const int kk = kb + kr;
      float4 v = make_float4(0.f, 0.f, 0.f, 0.f);
      if (kk < K && j < HID)             // j=296 reads 296..299; j>=300 -> 0
        v = *(const float4*)(Wm + (size_t)kk * HID + j);
      *(float4*)(W_s + kr * WC + j) = v;
    }
    __syncthreads();
    // ---- micro kernel ----
    #pragma unroll
    for (int kq = 0; kq < 8; ++kq) {
      float4 Af[4];
      #pragma unroll
      for (int i = 0; i < 4; ++i) {
        const int e = ty * 4 + i;
        Af[i] = *(const float4*)(A_s + e * 36 + ((kq ^ ((e >> 2) & 7)) << 2));
      }
      #pragma unroll
      for (int q = 0; q < 4; ++q) {
        const int krow = (kq << 2) + q;
        float4 Wf[5];
        #pragma unroll
        for (int p = 0; p < 5; ++p)
          Wf[p] = *(const float4*)(W_s + krow * WC + (tx << 2) + p * 64);
        #pragma unroll
        for (int i = 0; i < 4; ++i) {
          const float av = ((const float*)&Af[i])[q];
          #pragma unroll
          for (int p = 0; p < 5; ++p) {
            const float* w = (const float*)&Wf[p];
            #pragma unroll
            for (int jj = 0; jj < 4; ++jj)
              acc[i][p][jj] = fmaf(av, w[jj], acc[i][p][jj]);
          }
        }
      }
    }
    __syncthreads();
  }
  // ---- epilogue (writes own rows only; after all reads of this tile) ----
  #pragma unroll
  for (int i = 0; i < 4; ++i) {
    const int r = r0 + ty * 4 + i;
    if (MODE == 2 && r >= nrows) continue;
    #pragma unroll
    for (int p = 0; p < 5; ++p) {
      const int j = (tx << 2) + p * 64;
      if (j >= HID) continue;
      const float4 bv = *(const float4*)(bias + j);
      float vals[4];
      #pragma unroll
      for (int jj = 0; jj < 4; ++jj) vals[jj] = acc[i][p][jj] + ((const float*)&bv)[jj];
      if (MODE == 1) {
        const ushort4 h0v = *(const ushort4*)(h0 + (size_t)r * HID + j);
        vals[0] += bf2f(h0v.x); vals[1] += bf2f(h0v.y);
        vals[2] += bf2f(h0v.z); vals[3] += bf2f(h0v.w);
      }
      #pragma unroll
      for (int jj = 0; jj < 4; ++jj) vals[jj] = vals[jj] > 0.f ? vals[jj] : 0.f;
      if (MODE == 2) {
        *(float4*)(outF + (size_t)r * HID + j) =
            make_float4(vals[0], vals[1], vals[2], vals[3]);
      } else {
        ushort4 o;
        o.x = f2bf(vals[0]); o.y = f2bf(vals[1]);
        o.z = f2bf(vals[2]); o.w = f2bf(vals[3]);
        *(ushort4*)(outA + (size_t)r * HID + j) = o;
        if (MODE == 0) *(ushort4*)(outB + (size_t)r * HID + j) = o;
      }
    }
  }
}

// ---------------- output init + fused dot/pool ----------------
__global__ void init_out_kernel(float* __restrict__ out, const float* __restrict__ b_ffn) {
  int t = threadIdx.x;
  if (t < NG) out[t] = b_ffn[0];
}

__global__ void dotpool_kernel(const float* __restrict__ hn, const float* __restrict__ wffn,
                               const int* __restrict__ batch, float* __restrict__ out) {
  const int wave = threadIdx.x >> 6, lane = threadIdx.x & 63;
  const int v = blockIdx.x * 4 + wave;
  if (v >= NN) return;
  float s = 0.f;
  for (int j = lane; j < HID; j += 64) s += hn[(size_t)v * HID + j] * wffn[j];
  #pragma unroll
  for (int off = 32; off > 0; off >>= 1) s += __shfl_down(s, off, 64);
  if (lane == 0) atomicAdd(&out[batch[v]], s);
}

// ---------------- launch ----------------
extern "C" void kernel_launch(void* const* d_in, const int* in_sizes, int n_in,
                              void* d_out, int out_size, void* d_ws, size_t ws_size,
                              hipStream_t stream) {
  const float* x     = (const float*)d_in[0];
  const int*   eidx  = (const int*)d_in[1];
  const float* eattr = (const float*)d_in[2];
  const int*   batch = (const int*)d_in[3];
  const float* W_ei  = (const float*)d_in[4];
  const float* b_ei  = (const float*)d_in[5];
  const float* Ws    = (const float*)d_in[6];
  const float* bs    = (const float*)d_in[7];
  const float* W_en  = (const float*)d_in[8];
  const float* b_en  = (const float*)d_in[9];
  const float* W_ffn = (const float*)d_in[10];
  const float* b_ffn = (const float*)d_in[11];
  float* out = (float*)d_out;

  const int* row  = eidx;
  const int* colv = eidx + NE;

  // workspace layout (~217 MB total)
  char* ws = (char*)d_ws;
  unsigned short* h0 = (unsigned short*)(ws + 0);              //  96,000,000 B
  unsigned short* h  = (unsigned short*)(ws + 96000000ull);    //  96,000,000 B
  float* abuf        = (float*)(ws + 192000000ull);            //  12,000,000 B
  float* hn          = (float*)(ws + 204000000ull);            //  12,000,000 B
  int* indptr        = (int*)(ws + 216000000ull);              //      40,004 B
  int* cnt           = (int*)(ws + 216040192ull);              //      40,000 B
  int* eids          = (int*)(ws + 216080384ull);              //     640,000 B

  // CSR over col (reused by all 4 segment_sums); scatter restores cnt to 0
  zero_kernel<<<(NN + 255) / 256, 256, 0, stream>>>(cnt, NN);
  hist_kernel<<<NE / 256, 256, 0, stream>>>(colv, cnt);
  scan_kernel<<<1, 1024, 0, stream>>>(cnt, indptr);
  scatter_kernel<<<NE / 256, 256, 0, stream>>>(colv, indptr, cnt, eids);

  // h0 = relu([x[row]|ea] @ W_ei + b_ei); h = h0
  gemm_kernel<0><<<NE / BR, 256, 0, stream>>>(
      x, row, eattr, nullptr, nullptr, nullptr, W_ei, b_ei, h0, h, nullptr, NE, NF + EF);

  for (int l = 0; l < 3; ++l) {
    segsum_kernel<<<NN, 256, 0, stream>>>(h, indptr, eids, abuf);
    gemm_kernel<1><<<NE / BR, 256, 0, stream>>>(
        nullptr, row, nullptr, abuf, h, h0,
        Ws + (size_t)l * HID * HID, bs + (size_t)l * HID,
        h, nullptr, nullptr, NE, HID);            // in-place update of h
  }

  // s = segsum(h, col); hn = relu([x|s] @ W_en + b_en)
  segsum_kernel<<<NN, 256, 0, stream>>>(h, indptr, eids, abuf);
  gemm_kernel<2><<<(NN + BR - 1) / BR, 256, 0, stream>>>(
      x, nullptr, abuf, nullptr, nullptr, nullptr, W_en, b_en,
      nullptr, nullptr, hn, NN, NF + HID);

  // out[g] = b_ffn + sum_{batch[v]=g} hn[v] . W_ffn
  init_out_kernel<<<1, 64, 0, stream>>>(out, b_ffn);
  dotpool_kernel<<<NN / 4, 256, 0, stream>>>(hn, W_ffn, batch, out);
}

// Round 3
// 899.603 us; speedup vs baseline: 4.3944x; 4.3944x over previous
//
#include <hip/hip_runtime.h>
#include <stdint.h>

#define NN 10000      // nodes
#define NE 160000     // edges (paired: e and e^1 are fwd/rev)
#define HID 300
#define NF 133
#define EF 14
#define NG 64

#define BR 64         // edge rows per GEMM block
#define NT 19         // n-tiles of 16 (304 padded cols)
#define WGRAN (NT*64) // 1216 16B-granules of W per k-step

typedef __bf16 bf16x8 __attribute__((ext_vector_type(8)));
typedef float f32x4 __attribute__((ext_vector_type(4)));

union GR { bf16x8 v; unsigned short s[8]; uint4 u; };

__device__ __forceinline__ float bf2f(unsigned short u) {
  union { unsigned int i; float f; } x; x.i = ((unsigned int)u) << 16; return x.f;
}
__device__ __forceinline__ unsigned short f2bf(float f) {
  union { float f; unsigned int i; } x; x.f = f;
  unsigned int r = x.i + 0x7fffu + ((x.i >> 16) & 1u);
  return (unsigned short)(r >> 16);
}

// ---------------- small utilities ----------------
__global__ void zero_kernel(int* __restrict__ p, int n) {
  int i = blockIdx.x * 256 + threadIdx.x;
  if (i < n) p[i] = 0;
}

// ---------------- CSR build over col ----------------
__global__ void hist_kernel(const int* __restrict__ col, int* __restrict__ cnt) {
  int e = blockIdx.x * 256 + threadIdx.x;
  if (e < NE) atomicAdd(&cnt[col[e]], 1);
}

__global__ void scan_kernel(const int* __restrict__ cnt, int* __restrict__ indptr) {
  __shared__ int part[1024];
  int t = threadIdx.x;
  int base = t * 10;
  int loc[10];
  int s = 0;
  #pragma unroll
  for (int i = 0; i < 10; ++i) {
    int n = base + i;
    int v = (n < NN) ? cnt[n] : 0;
    loc[i] = s; s += v;
  }
  part[t] = s;
  __syncthreads();
  for (int off = 1; off < 1024; off <<= 1) {
    int v = part[t];
    int u = (t >= off) ? part[t - off] : 0;
    __syncthreads();
    part[t] = v + u;
    __syncthreads();
  }
  int pre = (t == 0) ? 0 : part[t - 1];
  #pragma unroll
  for (int i = 0; i < 10; ++i) {
    int n = base + i;
    if (n <= NN) indptr[n] = pre + loc[i];
  }
}

// consumes cnt back to zero (self-restoring across graph replays)
__global__ void scatter_kernel(const int* __restrict__ col, const int* __restrict__ indptr,
                               int* __restrict__ cnt, int* __restrict__ eids) {
  int e = blockIdx.x * 256 + threadIdx.x;
  if (e < NE) {
    int v = col[e];
    int p = atomicSub(&cnt[v], 1) - 1;
    eids[indptr[v] + p] = e;
  }
}

// ---------------- segment_sum(h[bf16], col) -> a[f32] via CSR ----------------
__global__ void segsum_kernel(const unsigned short* __restrict__ h,
                              const int* __restrict__ indptr, const int* __restrict__ eids,
                              float* __restrict__ a) {
  int v = blockIdx.x;
  int t = threadIdx.x;
  int beg = indptr[v], end = indptr[v + 1];
  float s0 = 0.f, s1 = 0.f;
  for (int p = beg; p < end; ++p) {
    int e = eids[p];
    const unsigned short* hr = h + (size_t)e * HID;
    s0 += bf2f(hr[t]);
    if (t < HID - 256) s1 += bf2f(hr[256 + t]);
  }
  a[(size_t)v * HID + t] = s0;
  if (t < HID - 256) a[(size_t)v * HID + 256 + t] = s1;
}

// ---------------- weight pre-transpose into MFMA fragment order -------------
// dst granule (kt,nt,lane l) holds W[kt*32 + (l>>4)*8 + i][nt*16 + (l&15)], i=0..7
__global__ void wtrans_kernel(const float* __restrict__ W, int K,
                              unsigned short* __restrict__ dst) {
  const int b = blockIdx.x;          // kt*NT + nt
  const int l = threadIdx.x;         // 0..63
  const int kt = b / NT, nt = b - kt * NT;
  const int k0 = kt * 32 + ((l >> 4) << 3);
  const int n  = (nt << 4) + (l & 15);
  GR g;
  #pragma unroll
  for (int i = 0; i < 8; ++i) {
    const int k = k0 + i;
    float f = (k < K && n < HID) ? W[(size_t)k * HID + n] : 0.f;
    g.s[i] = f2bf(f);
  }
  *(uint4*)(dst + ((size_t)(b * 64 + l) << 3)) = g.u;
}

// ---------------- MFMA GEMM: 64 rows x 304 cols per block -------------------
// MODE 0: edge_init  h0 = relu([x[row]|ea] @ W + b); also copy into h
// MODE 1: conv       h[e] = relu((a[row[e]] - bf(h[e^1])) @ W + b + bf(h0[e]))
//                    in-place on h (block owns full rows; reads precede writes)
// MODE 2: node MLP   hn = relu([x|s] @ W + b)  (f32 out)
template<int MODE>
__global__ __launch_bounds__(256, 2)
void gemm_kernel(const float* __restrict__ xin,
                 const int* __restrict__ rowidx,
                 const float* __restrict__ aux,        // MODE0: edge_attr ; MODE2: s
                 const float* __restrict__ agg,        // MODE1: a
                 const unsigned short* hcur,           // MODE1 in (aliases outA)
                 const unsigned short* __restrict__ h0,
                 const unsigned short* __restrict__ wbt,  // fragment-ordered bf16 W^T
                 const float* __restrict__ bias,
                 unsigned short* outA,
                 unsigned short* outB,
                 float* __restrict__ outF,
                 int ktiles)
{
  __shared__ unsigned short W_s[WGRAN * 8];  // 19456 B
  __shared__ unsigned short A_sm[256 * 8];   //  4096 B
  __shared__ int rowv[BR];

  const int t = threadIdx.x;
  const int l = t & 63;
  const int wave = t >> 6;
  const int r0 = blockIdx.x * BR;

  // thread -> A-granule mapping (byte t*16 in A_sm is lane-linear per 16-row tile)
  const int ag_e  = ((t >> 6) << 4) | (t & 15);  // edge row 0..63
  const int ag_k8 = (t >> 4) & 3;                // k-block-of-8 within k-step

  if (MODE != 2 && t < BR) rowv[t] = rowidx[r0 + t];
  __syncthreads();

  const int nt0 = wave * 5;
  const int ntc = (wave == 3) ? 4 : 5;

  f32x4 acc[5][4];
  #pragma unroll
  for (int ni = 0; ni < 5; ++ni)
    #pragma unroll
    for (int et = 0; et < 4; ++et) acc[ni][et] = (f32x4)0.f;

  for (int kt = 0; kt < ktiles; ++kt) {
    const int kb = kt * 32;
    // ---- stage W: contiguous copy of 1216 granules ----
    #pragma unroll
    for (int i = 0; i < 5; ++i) {
      const int gr = t + (i << 8);
      if (gr < WGRAN) {
        const uint4 v = *(const uint4*)(wbt + (((size_t)kt * WGRAN + gr) << 3));
        *(uint4*)((char*)W_s + gr * 16) = v;
      }
    }
    // ---- stage A: one granule (8 k x 1 row) per thread ----
    {
      const int k0 = kb + (ag_k8 << 3);
      GR g;
      if (MODE == 1) {
        const int r  = rowv[ag_e];
        const int ep = (r0 + ag_e) ^ 1;
        if (k0 + 8 <= HID) {
          const float4 a0 = *(const float4*)(agg + (size_t)r * HID + k0);
          const float4 a1 = *(const float4*)(agg + (size_t)r * HID + k0 + 4);
          const ushort4 hv0 = *(const ushort4*)(hcur + (size_t)ep * HID + k0);
          const ushort4 hv1 = *(const ushort4*)(hcur + (size_t)ep * HID + k0 + 4);
          g.s[0] = f2bf(a0.x - bf2f(hv0.x)); g.s[1] = f2bf(a0.y - bf2f(hv0.y));
          g.s[2] = f2bf(a0.z - bf2f(hv0.z)); g.s[3] = f2bf(a0.w - bf2f(hv0.w));
          g.s[4] = f2bf(a1.x - bf2f(hv1.x)); g.s[5] = f2bf(a1.y - bf2f(hv1.y));
          g.s[6] = f2bf(a1.z - bf2f(hv1.z)); g.s[7] = f2bf(a1.w - bf2f(hv1.w));
        } else {
          #pragma unroll
          for (int i = 0; i < 8; ++i) {
            const int k = k0 + i; float f = 0.f;
            if (k < HID) f = agg[(size_t)r * HID + k] - bf2f(hcur[(size_t)ep * HID + k]);
            g.s[i] = f2bf(f);
          }
        }
      } else if (MODE == 0) {
        const int r = rowv[ag_e];
        #pragma unroll
        for (int i = 0; i < 8; ++i) {
          const int k = k0 + i; float f = 0.f;
          if (k < NF) f = xin[(size_t)r * NF + k];
          else if (k < NF + EF) f = aux[(size_t)(r0 + ag_e) * EF + (k - NF)];
          g.s[i] = f2bf(f);
        }
      } else {
        const int node = r0 + ag_e;
        #pragma unroll
        for (int i = 0; i < 8; ++i) {
          const int k = k0 + i; float f = 0.f;
          if (node < NN) {
            if (k < NF) f = xin[(size_t)node * NF + k];
            else if (k < NF + HID) f = aux[(size_t)node * HID + (k - NF)];
          }
          g.s[i] = f2bf(f);
        }
      }
      *(uint4*)((char*)A_sm + t * 16) = g.u;
    }
    __syncthreads();
    // ---- compute: 4 edge frags reused across this wave's n-tiles ----
    bf16x8 ef[4];
    #pragma unroll
    for (int et = 0; et < 4; ++et)
      ef[et] = *(const bf16x8*)((const char*)A_sm + et * 1024 + l * 16);
    #pragma unroll
    for (int ni = 0; ni < 5; ++ni) {
      if (ni < ntc) {
        const bf16x8 wf = *(const bf16x8*)((const char*)W_s + (nt0 + ni) * 1024 + l * 16);
        #pragma unroll
        for (int et = 0; et < 4; ++et)
          acc[ni][et] = __builtin_amdgcn_mfma_f32_16x16x32_bf16(wf, ef[et], acc[ni][et], 0, 0, 0);
      }
    }
    __syncthreads();
  }

  // ---- epilogue: lane l holds C[e = et*16 + (l&15)][n = nt*16 + (l>>4)*4 + r] ----
  #pragma unroll
  for (int ni = 0; ni < 5; ++ni) {
    if (ni >= ntc) continue;
    const int nt = nt0 + ni;
    const int n = (nt << 4) + ((l >> 4) << 2);
    if (n >= HID) continue;                      // nt=18, lane-group 3 only
    const float4 bv = *(const float4*)(bias + n);
    #pragma unroll
    for (int et = 0; et < 4; ++et) {
      const int e = r0 + (et << 4) + (l & 15);
      if (MODE == 2 && e >= NN) continue;
      float v0 = acc[ni][et][0] + bv.x;
      float v1 = acc[ni][et][1] + bv.y;
      float v2 = acc[ni][et][2] + bv.z;
      float v3 = acc[ni][et][3] + bv.w;
      if (MODE == 1) {
        const ushort4 hv = *(const ushort4*)(h0 + (size_t)e * HID + n);
        v0 += bf2f(hv.x); v1 += bf2f(hv.y); v2 += bf2f(hv.z); v3 += bf2f(hv.w);
      }
      v0 = v0 > 0.f ? v0 : 0.f; v1 = v1 > 0.f ? v1 : 0.f;
      v2 = v2 > 0.f ? v2 : 0.f; v3 = v3 > 0.f ? v3 : 0.f;
      if (MODE == 2) {
        *(float4*)(outF + (size_t)e * HID + n) = make_float4(v0, v1, v2, v3);
      } else {
        ushort4 o; o.x = f2bf(v0); o.y = f2bf(v1); o.z = f2bf(v2); o.w = f2bf(v3);
        *(ushort4*)(outA + (size_t)e * HID + n) = o;
        if (MODE == 0) *(ushort4*)(outB + (size_t)e * HID + n) = o;
      }
    }
  }
}

// ---------------- output init + fused dot/pool ----------------
__global__ void init_out_kernel(float* __restrict__ out, const float* __restrict__ b_ffn) {
  int t = threadIdx.x;
  if (t < NG) out[t] = b_ffn[0];
}

__global__ void dotpool_kernel(const float* __restrict__ hn, const float* __restrict__ wffn,
                               const int* __restrict__ batch, float* __restrict__ out) {
  const int wave = threadIdx.x >> 6, lane = threadIdx.x & 63;
  const int v = blockIdx.x * 4 + wave;
  if (v >= NN) return;
  float s = 0.f;
  for (int j = lane; j < HID; j += 64) s += hn[(size_t)v * HID + j] * wffn[j];
  #pragma unroll
  for (int off = 32; off > 0; off >>= 1) s += __shfl_down(s, off, 64);
  if (lane == 0) atomicAdd(&out[batch[v]], s);
}

// ---------------- launch ----------------
extern "C" void kernel_launch(void* const* d_in, const int* in_sizes, int n_in,
                              void* d_out, int out_size, void* d_ws, size_t ws_size,
                              hipStream_t stream) {
  const float* x     = (const float*)d_in[0];
  const int*   eidx  = (const int*)d_in[1];
  const float* eattr = (const float*)d_in[2];
  const int*   batch = (const int*)d_in[3];
  const float* W_ei  = (const float*)d_in[4];
  const float* b_ei  = (const float*)d_in[5];
  const float* Ws    = (const float*)d_in[6];
  const float* bs    = (const float*)d_in[7];
  const float* W_en  = (const float*)d_in[8];
  const float* b_en  = (const float*)d_in[9];
  const float* W_ffn = (const float*)d_in[10];
  const float* b_ffn = (const float*)d_in[11];
  float* out = (float*)d_out;

  const int* row  = eidx;
  const int* colv = eidx + NE;

  // workspace layout (~218 MB total)
  char* ws = (char*)d_ws;
  unsigned short* h0 = (unsigned short*)(ws + 0);              //  96,000,000 B
  unsigned short* h  = (unsigned short*)(ws + 96000000ull);    //  96,000,000 B
  float* abuf        = (float*)(ws + 192000000ull);            //  12,000,000 B
  float* hn          = (float*)(ws + 204000000ull);            //  12,000,000 B
  int* indptr        = (int*)(ws + 216000000ull);              //      40,004 B
  int* cnt           = (int*)(ws + 216040192ull);              //      40,000 B
  int* eids          = (int*)(ws + 216080384ull);              //     640,000 B
  unsigned short* wbt0 = (unsigned short*)(ws + 216720384ull); //      97,280 B (5 kt)
  unsigned short* wbtC = (unsigned short*)(ws + 216817664ull); //  3x 194,560 B (10 kt)
  unsigned short* wbtN = (unsigned short*)(ws + 217401344ull); //     272,384 B (14 kt)

  // CSR over col (scatter restores cnt to 0)
  zero_kernel<<<(NN + 255) / 256, 256, 0, stream>>>(cnt, NN);
  hist_kernel<<<NE / 256, 256, 0, stream>>>(colv, cnt);
  scan_kernel<<<1, 1024, 0, stream>>>(cnt, indptr);
  scatter_kernel<<<NE / 256, 256, 0, stream>>>(colv, indptr, cnt, eids);

  // weight pre-transposes (bf16, MFMA fragment order)
  wtrans_kernel<<<5 * NT, 64, 0, stream>>>(W_ei, NF + EF, wbt0);
  for (int lyr = 0; lyr < 3; ++lyr)
    wtrans_kernel<<<10 * NT, 64, 0, stream>>>(Ws + (size_t)lyr * HID * HID, HID,
                                              wbtC + (size_t)lyr * 10 * WGRAN * 8);
  wtrans_kernel<<<14 * NT, 64, 0, stream>>>(W_en, NF + HID, wbtN);

  // h0 = relu([x[row]|ea] @ W_ei + b_ei); h = h0
  gemm_kernel<0><<<NE / BR, 256, 0, stream>>>(
      x, row, eattr, nullptr, nullptr, nullptr, wbt0, b_ei, h0, h, nullptr, 5);

  for (int lyr = 0; lyr < 3; ++lyr) {
    segsum_kernel<<<NN, 256, 0, stream>>>(h, indptr, eids, abuf);
    gemm_kernel<1><<<NE / BR, 256, 0, stream>>>(
        nullptr, row, nullptr, abuf, h, h0,
        wbtC + (size_t)lyr * 10 * WGRAN * 8, bs + (size_t)lyr * HID,
        h, nullptr, nullptr, 10);                 // in-place update of h
  }

  // s = segsum(h, col); hn = relu([x|s] @ W_en + b_en)
  segsum_kernel<<<NN, 256, 0, stream>>>(h, indptr, eids, abuf);
  gemm_kernel<2><<<(NN + BR - 1) / BR, 256, 0, stream>>>(
      x, nullptr, abuf, nullptr, nullptr, nullptr, wbtN, b_en,
      nullptr, nullptr, hn, 14);

  // out[g] = b_ffn + sum_{batch[v]=g} hn[v] . W_ffn
  init_out_kernel<<<1, 64, 0, stream>>>(out, b_ffn);
  dotpool_kernel<<<NN / 4, 256, 0, stream>>>(hn, W_ffn, batch, out);
}